// Round 12
// baseline (125.547 us; speedup 1.0000x reference)
//
#include <hip/hip_runtime.h>
#include <stdint.h>

#define TT 4
#define BB 16
#define CC 512
#define VV 1024
#define OO 1536   // stacked q,k,v output channels

typedef __attribute__((ext_vector_type(4)))  int      i32x4;
typedef __attribute__((ext_vector_type(4)))  float    f32x4;
typedef __attribute__((ext_vector_type(16))) uint8_t  u8x16;
typedef __attribute__((ext_vector_type(8)))  uint8_t  u8x8;
typedef __attribute__((ext_vector_type(8)))  int8_t   i8x8;

__device__ __forceinline__ float bf2f(unsigned short u){
  union { unsigned int i; float f; } x; x.i = ((unsigned int)u) << 16; return x.f;
}
__device__ __forceinline__ unsigned short f2bf(float f){
  union { float f; unsigned int i; } x; x.f = f;
  unsigned int u = x.i;
  return (unsigned short)((u + 0x7fffu + ((u >> 16) & 1u)) >> 16);
}

// async global->LDS, 16B/lane; LDS dest wave-uniform base + lane*16
__device__ __forceinline__ void g2lds16(const void* g, void* l){
  __builtin_amdgcn_global_load_lds(
      (const __attribute__((address_space(1))) unsigned int*)g,
      (__attribute__((address_space(3))) unsigned int*)l,
      16, 0, 0);
}

// ---- head LIF (blocks 0..2047) + weight prep (blocks 2048..2431) fused ----
__global__ __launch_bounds__(256) void k_head_lif_prep(
    const float* __restrict__ x, int8_t* __restrict__ xs8,
    const float* __restrict__ Wq, const float* __restrict__ sq, const float* __restrict__ bq,
    const float* __restrict__ Wk, const float* __restrict__ sk, const float* __restrict__ bk,
    const float* __restrict__ Wv, const float* __restrict__ sv, const float* __restrict__ bv,
    const float* __restrict__ Wp, const float* __restrict__ sp,
    int8_t* __restrict__ Wq8, float* __restrict__ scales, float* __restrict__ bias,
    unsigned short* __restrict__ WpT, int* __restrict__ flags)
{
  int bid = blockIdx.x;
  int tid = threadIdx.x;

  if (bid >= 2048) {
    if (bid < 2176) {
      // per-channel i8 quant of BN-folded Wqkv: 12 o-channels per block
      int idx = bid - 2048;
      int lane = tid & 63, wvv = tid >> 6;
      if (idx == 0 && tid < 2) flags[tid] = 0;
      #pragma unroll
      for (int p = 0; p < 3; ++p) {
        int o = idx*12 + p*4 + wvv;
        const float *W, *s, *b; int oo;
        if (o < 512)       { W = Wq; s = sq; b = bq; oo = o; }
        else if (o < 1024) { W = Wk; s = sk; b = bk; oo = o - 512; }
        else               { W = Wv; s = sv; b = bv; oo = o - 1024; }
        float sv_ = s[oo];
        float w[8]; float amax = 0.f;
        #pragma unroll
        for (int j=0;j<8;j++){
          w[j] = W[oo*512 + lane*8 + j] * sv_;
          amax = fmaxf(amax, fabsf(w[j]));
        }
        #pragma unroll
        for (int off=32; off; off>>=1) amax = fmaxf(amax, __shfl_xor(amax, off));
        float scale = (amax > 0.f) ? amax*(1.f/127.f) : 1.f;
        float inv = 1.f/scale;
        i8x8 q;
        #pragma unroll
        for (int j=0;j<8;j++){
          int qi = (int)rintf(w[j]*inv);
          qi = qi > 127 ? 127 : (qi < -127 ? -127 : qi);
          q[j] = (int8_t)qi;
        }
        *(i8x8*)(Wq8 + o*512 + lane*8) = q;
        if (lane == 0){ scales[o] = scale; bias[o] = b[oo]; }
      }
    } else {
      // fallback-only: transposed bf16 Wp with sp folded
      int j0 = (bid - 2176)*1024 + tid*4;
      #pragma unroll
      for (int i=0;i<4;i++){
        int j = j0 + i; int o = j >> 9, c = j & 511;
        WpT[c*512 + o] = f2bf(Wp[j]*sp[o]);
      }
    }
    return;
  }

  // ---- head LIF: fp32-exact, i8 spikes transposed to xs8[t][b][v][c] ----
  int vt = bid & 15, ct = (bid >> 4) & 7, b = bid >> 7;
  int c0 = ct*64, v0 = vt*64;
  __shared__ uint8_t sp_[64][68];
  int cr = tid >> 4;         // 0..15
  int vr = tid & 15;         // 0..15
  float st[4][4];
  #pragma unroll
  for (int i=0;i<4;i++) for (int j=0;j<4;j++) st[i][j]=0.f;
  for (int t=0;t<TT;t++){
    size_t tb = (size_t)t*BB + b;
    const float* xt = x + (tb*CC + c0) * (size_t)VV + v0;
    #pragma unroll
    for (int i=0;i<4;i++){
      const float4 xv = *(const float4*)(xt + (size_t)(cr + i*16)*VV + vr*4);
      const float xe[4] = {xv.x, xv.y, xv.z, xv.w};
      #pragma unroll
      for (int j=0;j<4;j++){
        float vv = st[i][j];
        vv = vv + (xe[j] - vv) * 0.5f;       // exact: /2 == *0.5
        bool s = (vv >= 1.0f);
        sp_[cr + i*16][vr*4 + j] = s ? 1 : 0;
        st[i][j] = s ? 0.f : vv;             // hard reset
      }
    }
    __syncthreads();
    int v_loc = tid >> 2;
    int c16 = (tid & 3) * 16;
    u8x16 o0;
    #pragma unroll
    for (int j=0;j<16;j++) o0[j] = sp_[c16 + j][v_loc];
    *(u8x16*)(xs8 + (tb*VV + v0 + v_loc)*(size_t)CC + c0 + c16) = o0;
    __syncthreads();
  }
}

// ---- fused i8 GEMM + t-loop LIF + (STORE=0) in-region bp-broadcast out-write.
//      B: LDS-resident 64KB staged once; A: LDS dbuf 2x8KB; counted-vmcnt
//      barrier pair. Storer blocks (orig<1024) write one out-row (4KB NT) per
//      K-step INSIDE the B1..B2 region: at B1 the previous store is 1 MFMA
//      phase old, so vmcnt(3) never forces a fresh store to retire. ----
template<int STORE>
__global__ __launch_bounds__(256, 2) void k_gemm_fused(
    const int8_t* __restrict__ xs8, const int8_t* __restrict__ Wq8,
    const float* __restrict__ scales, const float* __restrict__ bias,
    const float* __restrict__ bp, float* __restrict__ outp,
    uint8_t* __restrict__ spk, int* __restrict__ flags)
{
  if (STORE && flags[0] == 0) return;
  int orig = blockIdx.x;
  int tid = threadIdx.x, lane = tid & 63, wv = tid >> 6;

  const bool storer = (!STORE) && (orig < 1024);

  // preload the 32 bp values this block broadcasts (rows R=orig*32+g, o=R&511;
  // base=(orig*32)&511 is 32-aligned so the 32 floats never wrap 512).
  // Issued before ALL staging: compiler's own wait for these lands when actual
  // outstanding ~2 (post-B1), i.e. free.
  float bcv[32];
  if (storer){
    int base = (orig * 32) & 511;
    #pragma unroll
    for (int i=0;i<8;i++){
      f32x4 v = *(const f32x4*)(bp + base + i*4);
      bcv[i*4+0]=v[0]; bcv[i*4+1]=v[1]; bcv[i*4+2]=v[2]; bcv[i*4+3]=v[3];
    }
  }

  // bijective XCD swizzle: 1536 wgs, 192/XCD; o-tiles innermost -> A reuse in L2
  int wg = (orig >> 3) + (orig & 7) * 192;
  int ot = wg % 12;
  int r  = wg / 12;
  int vt = r & 7;
  int b  = r >> 3;
  int o0 = ot*128, v0 = vt*128;

  // LDS: B resident [128 rows][512B] swizzled (0..65536), A dbuf 2x8KB (65536..81920)
  __shared__ __attribute__((aligned(16))) uint8_t lds[81920];

  int wm = wv >> 1, wn = wv & 1;

  const int8_t* Bg = Wq8 + (size_t)o0 * CC;

  // stage B once: chunk j = 2 rows of 512B; swizzle c16 ^= (orow&7)
  {
    int orl = lane >> 5;           // 0..1
    int sl  = lane & 31;           // 16B slot within row
    #pragma unroll
    for (int i=0;i<16;i++){
      int j = wv*16 + i;
      int orow = j*2 + orl;
      int c16 = sl ^ (orow & 7);
      g2lds16(Bg + (size_t)orow*CC + (c16 << 4), lds + j*1024);
    }
  }

  auto STAGE_A = [&](int buf, const int8_t* base, int k0){
    int rl  = lane >> 2;                       // row within 16-row chunk
    int c16 = (lane & 3) ^ ((lane >> 3) & 3);  // pre-swizzled source slot
    #pragma unroll
    for (int i=0;i<2;i++){
      int j = wv*2 + i;
      g2lds16(base + (size_t)(j*16 + rl)*CC + k0 + (c16 << 4),
              lds + 65536 + buf*8192 + j*1024);
    }
  };
  auto READB = [&](int ks, i32x4* dst){
    #pragma unroll
    for (int n=0;n<4;n++){
      int orow = wn*64 + n*16 + (lane & 15);
      int slot = (((ks & 7) << 2) + (lane >> 4)) ^ (lane & 7);
      dst[n] = *(const i32x4*)(lds + orow*512 + (slot << 4));
    }
  };

  i32x4 acc[4][4];
  float st[4][4][4];
  #pragma unroll
  for (int m=0;m<4;m++)
    #pragma unroll
    for (int n=0;n<4;n++){
      acc[m][n] = (i32x4){0,0,0,0};
      #pragma unroll
      for (int j=0;j<4;j++) st[m][n][j] = 0.f;
    }

  float sc[4], bi[4];
  #pragma unroll
  for (int n=0;n<4;n++){
    int og = o0 + wn*64 + n*16 + (lane & 15);
    sc[n] = scales[og];
    bi[n] = bias[og];
  }

  const int8_t* A0 = xs8 + ((size_t)b*VV + v0) * CC;
  STAGE_A(0, A0, 0);
  // no barrier here: first B1 (vmcnt+barrier) covers B and A0

  int anyspike = 0;
  #pragma unroll
  for (int t=0; t<TT; ++t){
    const int8_t* At = xs8 + ((size_t)(t*BB + b)*VV + v0) * CC;
    const int8_t* An = xs8 + ((size_t)((t+1)*BB + b)*VV + v0) * CC;
    #pragma unroll
    for (int ks=0; ks<8; ++ks){
      const int g = t*8 + ks;          // global step 0..31 (compile-time)
      int cur = ks & 1;

      bool staged = false;
      if (ks < 7)          { STAGE_A(cur^1, At, (ks+1)*64); staged = true; }
      else if (t < TT-1)   { STAGE_A(cur^1, An, 0);         staged = true; }

      // B1: acquire A-buf `cur` (RAW). Queue (storer, g>=1):
      //   L(g-1)a,b, S(g-1), L(g)a,b  -> vmcnt(3) retires L(g-1), leaves S(g-1).
      if (STORE) {
        __syncthreads();
      } else {
        if (staged) {
          if (storer && g >= 1) asm volatile("s_waitcnt vmcnt(3)" ::: "memory");
          else                  asm volatile("s_waitcnt vmcnt(2)" ::: "memory");
        } else {
          if (storer)           asm volatile("s_waitcnt vmcnt(1)" ::: "memory");
          else                  asm volatile("s_waitcnt vmcnt(0)" ::: "memory");
        }
        __builtin_amdgcn_s_barrier();
      }

      const uint8_t* bufA = lds + 65536 + cur*8192;
      i32x4 af[4], bfr[4];
      #pragma unroll
      for (int m=0;m<4;m++){
        int rr = wm*64 + m*16 + (lane & 15);
        int slot = (lane >> 4) ^ ((lane >> 1) & 3);
        af[m] = *(const i32x4*)(bufA + rr*64 + (slot << 4));
      }
      READB(ks, bfr);

      #pragma unroll
      for (int m=0;m<4;m++)
        #pragma unroll
        for (int n=0;n<4;n++)
          acc[m][n] = __builtin_amdgcn_mfma_i32_16x16x64_i8(af[m], bfr[n], acc[m][n], 0,0,0);

      // in-region broadcast store: row R = orig*32+g of out (tb=R>>9, o=R&511),
      // 4KB NT per block-step. Pinned inside B1..B2 by the asm memory clobbers.
      if (storer){
        size_t R = (size_t)orig*32 + g;
        float bvv = bcv[g];            // compile-time index (loops fully unrolled)
        f32x4 val = (f32x4){bvv, bvv, bvv, bvv};
        __builtin_nontemporal_store(val, (f32x4*)(outp + R*1024 + tid*4));
      }

      // B2: release A-buf `cur` (WAR): all my LDS reads done, then barrier
      if (!(t == TT-1 && ks == 7)) {
        if (STORE) {
          __syncthreads();
        } else {
          asm volatile("s_waitcnt lgkmcnt(0)" ::: "memory");
          __builtin_amdgcn_s_barrier();
        }
      }
    }
    // per-t epilogue: dequant + bias + LIF (registers only)
    size_t tb = (size_t)t*BB + b;
    #pragma unroll
    for (int m=0;m<4;m++)
      #pragma unroll
      for (int n=0;n<4;n++)
        #pragma unroll
        for (int j=0;j<4;j++){
          float y = (float)acc[m][n][j] * sc[n] + bi[n];
          float vv = st[m][n][j];
          vv = vv + (y - vv) * 0.5f;
          int s = (vv >= 1.0f) ? 1 : 0;
          anyspike |= s;
          st[m][n][j] = s ? 0.f : vv;
          acc[m][n][j] = 0;
          if (STORE){
            int v  = v0 + wm*64 + m*16 + ((lane >> 4) << 2) + j;
            int og = o0 + wn*64 + n*16 + (lane & 15);
            spk[(tb*VV + v)*(size_t)OO + og] = (uint8_t)s;
          }
        }
  }
  if (!STORE){
    unsigned long long any = __ballot(anyspike != 0);
    if (any != 0ull && lane == 0) atomicOr(flags, 1);
  }
}

// ---- gated attention path (runs only if any q/k/v spike) ----
__global__ __launch_bounds__(256) void k_kv(const uint8_t* __restrict__ spk,
                                            float* __restrict__ kv,
                                            const int* __restrict__ flags)
{
  if (flags[0] == 0) return;
  int bid = blockIdx.x;
  int h = bid & 7, b = (bid>>3) & 15, t = bid >> 7;
  size_t tb = (size_t)t*BB + b;
  const uint8_t* kb_g = spk + tb*VV*OO + 512  + h*64;
  const uint8_t* vb_g = spk + tb*VV*OO + 1024 + h*64;
  __shared__ __attribute__((aligned(16))) uint8_t kb[16][64];
  __shared__ __attribute__((aligned(16))) uint8_t vb[16][64];
  int tid = threadIdx.x;
  int d = tid >> 2, e0 = (tid & 3) * 16;
  float acc[16];
  #pragma unroll
  for (int i=0;i<16;i++) acc[i]=0.f;
  for (int n0=0;n0<VV;n0+=16){
    int arr = tid >> 7;
    int rr = (tid >> 3) & 15;
    int ch = (tid & 7) * 8;
    u8x8 val = *(const u8x8*)((arr ? vb_g : kb_g) + (size_t)(n0 + rr)*OO + ch);
    *(u8x8*)&(arr ? vb : kb)[rr][ch] = val;
    __syncthreads();
    #pragma unroll
    for (int nn=0;nn<16;nn++){
      if (kb[nn][d]) {
        #pragma unroll
        for (int i=0;i<16;i++) acc[i] += (vb[nn][e0+i] ? 1.0f : 0.0f);
      }
    }
    __syncthreads();
  }
  float* dst = kv + (((tb*8) + h)*64 + d)*(size_t)64 + e0;
  #pragma unroll
  for (int i=0;i<16;i++) dst[i] = acc[i];
}

__global__ __launch_bounds__(256) void k_o_alif(const uint8_t* __restrict__ spk,
                                                const float* __restrict__ kv,
                                                uint8_t* __restrict__ a,
                                                int* __restrict__ flags)
{
  if (flags[0] == 0) return;
  int bid = blockIdx.x;
  int nt = bid & 7, h = (bid>>3) & 7, b = bid >> 6;
  int n0 = nt * 128;
  __shared__ __attribute__((aligned(16))) float kvb[64][64];
  int tid = threadIdx.x;
  int nl = tid >> 1, e0 = (tid & 1) * 32;
  float st[32];
  #pragma unroll
  for (int i=0;i<32;i++) st[i]=0.f;
  int anyA = 0;
  for (int t=0;t<TT;t++){
    size_t tb = (size_t)t*BB + b;
    const f32x4* src = (const f32x4*)(kv + ((tb*8) + h)*(size_t)4096);
    #pragma unroll
    for (int i=0;i<4;i++) ((f32x4*)kvb)[tid + i*256] = src[tid + i*256];
    __syncthreads();
    const uint8_t* qrow = spk + (tb*VV + n0 + nl)*(size_t)OO + h*64;
    float accv[32];
    #pragma unroll
    for (int i=0;i<32;i++) accv[i]=0.f;
    for (int d8=0; d8<8; d8++){
      u8x8 qv = *(const u8x8*)(qrow + d8*8);
      #pragma unroll
      for (int jj=0;jj<8;jj++){
        if (qv[jj]) {
          int dd = d8*8 + jj;
          #pragma unroll
          for (int i=0;i<32;i++) accv[i] += kvb[dd][e0+i];
        }
      }
    }
    uint8_t* arow = a + (tb*VV + n0 + nl)*(size_t)CC + h*64 + e0;
    #pragma unroll
    for (int i=0;i<32;i++){
      float o = accv[i] * 0.125f;
      float vv = st[i];
      vv = vv + (o - vv)*0.5f;
      bool s = (vv >= 0.5f);
      st[i] = s ? 0.f : vv;
      arow[i] = s ? 1 : 0;
      anyA |= (int)s;
    }
    __syncthreads();
  }
  __shared__ int sA;
  if (tid==0) sA=0;
  __syncthreads();
  if (anyA) sA=1;
  __syncthreads();
  if (tid==0 && sA) atomicOr(flags+1, 1);
}

__global__ __launch_bounds__(256) void k_out_add(const uint8_t* __restrict__ a,
                                                 const unsigned short* __restrict__ WpT,
                                                 float* __restrict__ out,
                                                 const int* __restrict__ flags)
{
  if (flags[1] == 0) return;
  int bid = blockIdx.x;
  int vt = bid & 15, b = (bid>>4) & 15, t = bid >> 8;
  size_t tb = (size_t)t*BB + b;
  int v0 = vt*64;
  int tid = threadIdx.x;
  for (int vi=0; vi<64; vi++){
    int v = v0 + vi;
    const uint8_t* av = a + (tb*VV + v)*(size_t)CC;
    for (int c=0;c<CC;c++){
      if (av[c]) {
        #pragma unroll
        for (int i=0;i<2;i++){
          int o = tid + i*256;
          out[((tb*CC) + o)*(size_t)VV + v] += bf2f(WpT[c*512 + o]);
        }
      }
    }
  }
}

// ---------------- launch ------------------------------------------------------
extern "C" void kernel_launch(void* const* d_in, const int* in_sizes, int n_in,
                              void* d_out, int out_size, void* d_ws, size_t ws_size,
                              hipStream_t stream)
{
  (void)in_sizes; (void)n_in; (void)out_size;
  const float* x  = (const float*)d_in[0];
  const float* Wq = (const float*)d_in[1];
  const float* sq = (const float*)d_in[2];
  const float* bq = (const float*)d_in[3];
  const float* Wk = (const float*)d_in[4];
  const float* sk = (const float*)d_in[5];
  const float* bk = (const float*)d_in[6];
  const float* Wv = (const float*)d_in[7];
  const float* sv = (const float*)d_in[8];
  const float* bv = (const float*)d_in[9];
  const float* Wp = (const float*)d_in[10];
  const float* sp = (const float*)d_in[11];
  const float* bp = (const float*)d_in[12];
  float* out = (float*)d_out;
  uint8_t* ws = (uint8_t*)d_ws;

  if (ws_size < 177483792ull) return;

  int8_t*         xs8   = (int8_t*)(ws + 0);                   // 32 MiB
  int8_t*         Wq8   = (int8_t*)(ws + 33554432ull);         // 768 KiB
  float*          scales= (float*)(ws + 34340864ull);          // 6 KiB
  float*          bias  = (float*)(ws + 34347008ull);          // 6 KiB
  unsigned short* WpT   = (unsigned short*)(ws + 34353152ull); // 512 KiB
  float*          kv    = (float*)(ws + 34877440ull);          // 8 MiB
  uint8_t*        spk   = (uint8_t*)(ws + 43266048ull);        // 96 MiB (fallback)
  uint8_t*        abuf  = (uint8_t*)(ws + 143929344ull);       // 32 MiB (fallback)
  int*            flags = (int*)(ws + 177483776ull);           // 16 B

  k_head_lif_prep<<<2432,256,0,stream>>>(x, xs8, Wq,sq,bq, Wk,sk,bk, Wv,sv,bv,
                                         Wp,sp, Wq8, scales, bias, WpT, flags);
  k_gemm_fused<0><<<1536,256,0,stream>>>(xs8, Wq8, scales, bias, bp, out, spk, flags);
  k_gemm_fused<1><<<1536,256,0,stream>>>(xs8, Wq8, scales, bias, bp, out, spk, flags);
  k_kv<<<512,256,0,stream>>>(spk, kv, flags);
  k_o_alif<<<1024,256,0,stream>>>(spk, kv, abuf, flags);
  k_out_add<<<1024,256,0,stream>>>(abuf, WpT, out, flags);
}

// Round 13
// 93.354 us; speedup vs baseline: 1.3449x; 1.3449x over previous
//
#include <hip/hip_runtime.h>
#include <stdint.h>

#define TT 4
#define BB 16
#define CC 512
#define VV 1024
#define OO 1536   // stacked q,k,v output channels

typedef __attribute__((ext_vector_type(4)))  int      i32x4;
typedef __attribute__((ext_vector_type(4)))  float    f32x4;
typedef __attribute__((ext_vector_type(16))) uint8_t  u8x16;
typedef __attribute__((ext_vector_type(8)))  uint8_t  u8x8;
typedef __attribute__((ext_vector_type(8)))  int8_t   i8x8;

__device__ __forceinline__ float bf2f(unsigned short u){
  union { unsigned int i; float f; } x; x.i = ((unsigned int)u) << 16; return x.f;
}
__device__ __forceinline__ unsigned short f2bf(float f){
  union { float f; unsigned int i; } x; x.f = f;
  unsigned int u = x.i;
  return (unsigned short)((u + 0x7fffu + ((u >> 16) & 1u)) >> 16);
}

// async global->LDS, 16B/lane; LDS dest wave-uniform base + lane*16
__device__ __forceinline__ void g2lds16(const void* g, void* l){
  __builtin_amdgcn_global_load_lds(
      (const __attribute__((address_space(1))) unsigned int*)g,
      (__attribute__((address_space(3))) unsigned int*)l,
      16, 0, 0);
}

// ---- head LIF (blocks 0..2047) + weight prep (blocks 2048..2431) fused ----
__global__ __launch_bounds__(256) void k_head_lif_prep(
    const float* __restrict__ x, int8_t* __restrict__ xs8,
    const float* __restrict__ Wq, const float* __restrict__ sq, const float* __restrict__ bq,
    const float* __restrict__ Wk, const float* __restrict__ sk, const float* __restrict__ bk,
    const float* __restrict__ Wv, const float* __restrict__ sv, const float* __restrict__ bv,
    const float* __restrict__ Wp, const float* __restrict__ sp,
    int8_t* __restrict__ Wq8, float* __restrict__ scales, float* __restrict__ bias,
    unsigned short* __restrict__ WpT, int* __restrict__ flags)
{
  int bid = blockIdx.x;
  int tid = threadIdx.x;

  if (bid >= 2048) {
    if (bid < 2176) {
      // per-channel i8 quant of BN-folded Wqkv: 12 o-channels per block
      int idx = bid - 2048;
      int lane = tid & 63, wvv = tid >> 6;
      if (idx == 0 && tid < 2) flags[tid] = 0;
      #pragma unroll
      for (int p = 0; p < 3; ++p) {
        int o = idx*12 + p*4 + wvv;
        const float *W, *s, *b; int oo;
        if (o < 512)       { W = Wq; s = sq; b = bq; oo = o; }
        else if (o < 1024) { W = Wk; s = sk; b = bk; oo = o - 512; }
        else               { W = Wv; s = sv; b = bv; oo = o - 1024; }
        float sv_ = s[oo];
        float w[8]; float amax = 0.f;
        #pragma unroll
        for (int j=0;j<8;j++){
          w[j] = W[oo*512 + lane*8 + j] * sv_;
          amax = fmaxf(amax, fabsf(w[j]));
        }
        #pragma unroll
        for (int off=32; off; off>>=1) amax = fmaxf(amax, __shfl_xor(amax, off));
        float scale = (amax > 0.f) ? amax*(1.f/127.f) : 1.f;
        float inv = 1.f/scale;
        i8x8 q;
        #pragma unroll
        for (int j=0;j<8;j++){
          int qi = (int)rintf(w[j]*inv);
          qi = qi > 127 ? 127 : (qi < -127 ? -127 : qi);
          q[j] = (int8_t)qi;
        }
        *(i8x8*)(Wq8 + o*512 + lane*8) = q;
        if (lane == 0){ scales[o] = scale; bias[o] = b[oo]; }
      }
    } else {
      // fallback-only: transposed bf16 Wp with sp folded
      int j0 = (bid - 2176)*1024 + tid*4;
      #pragma unroll
      for (int i=0;i<4;i++){
        int j = j0 + i; int o = j >> 9, c = j & 511;
        WpT[c*512 + o] = f2bf(Wp[j]*sp[o]);
      }
    }
    return;
  }

  // ---- head LIF: fp32-exact, i8 spikes transposed to xs8[t][b][v][c] ----
  int vt = bid & 15, ct = (bid >> 4) & 7, b = bid >> 7;
  int c0 = ct*64, v0 = vt*64;
  __shared__ uint8_t sp_[64][68];
  int cr = tid >> 4;         // 0..15
  int vr = tid & 15;         // 0..15
  float st[4][4];
  #pragma unroll
  for (int i=0;i<4;i++) for (int j=0;j<4;j++) st[i][j]=0.f;
  for (int t=0;t<TT;t++){
    size_t tb = (size_t)t*BB + b;
    const float* xt = x + (tb*CC + c0) * (size_t)VV + v0;
    #pragma unroll
    for (int i=0;i<4;i++){
      const float4 xv = *(const float4*)(xt + (size_t)(cr + i*16)*VV + vr*4);
      const float xe[4] = {xv.x, xv.y, xv.z, xv.w};
      #pragma unroll
      for (int j=0;j<4;j++){
        float vv = st[i][j];
        vv = vv + (xe[j] - vv) * 0.5f;       // exact: /2 == *0.5
        bool s = (vv >= 1.0f);
        sp_[cr + i*16][vr*4 + j] = s ? 1 : 0;
        st[i][j] = s ? 0.f : vv;             // hard reset
      }
    }
    __syncthreads();
    int v_loc = tid >> 2;
    int c16 = (tid & 3) * 16;
    u8x16 o0;
    #pragma unroll
    for (int j=0;j<16;j++) o0[j] = sp_[c16 + j][v_loc];
    *(u8x16*)(xs8 + (tb*VV + v0 + v_loc)*(size_t)CC + c0 + c16) = o0;
    __syncthreads();
  }
}

// ---- fused i8 GEMM + t-loop LIF + (STORE=0) in-loop bp-broadcast out-write.
//      B: LDS-resident 64KB staged once; A: LDS dbuf 2x8KB; counted-vmcnt
//      barrier pair. Block orig stores out-row R = g*1536+orig at step g<21
//      (o = R&511 = orig&511 -> ONE block-uniform scalar bp value, no per-step
//      vector load, no indexed array). Store issued BEFORE the A-stage; B1
//      uses vmcnt(3) so the fresh store is never forced to retire. ----
template<int STORE>
__global__ __launch_bounds__(256, 2) void k_gemm_fused(
    const int8_t* __restrict__ xs8, const int8_t* __restrict__ Wq8,
    const float* __restrict__ scales, const float* __restrict__ bias,
    const float* __restrict__ bp, float* __restrict__ outp,
    uint8_t* __restrict__ spk, int* __restrict__ flags)
{
  if (STORE && flags[0] == 0) return;
  int orig = blockIdx.x;
  int tid = threadIdx.x, lane = tid & 63, wv = tid >> 6;

  // block-uniform bp value for all this block's bcast rows (scalar s_load)
  float bvv = 0.f;
  if (!STORE) bvv = bp[orig & 511];

  // bijective XCD swizzle: 1536 wgs, 192/XCD; o-tiles innermost -> A reuse in L2
  int wg = (orig >> 3) + (orig & 7) * 192;
  int ot = wg % 12;
  int r  = wg / 12;
  int vt = r & 7;
  int b  = r >> 3;
  int o0 = ot*128, v0 = vt*128;

  // LDS: B resident [128 rows][512B] swizzled (0..65536), A dbuf 2x8KB (65536..81920)
  __shared__ __attribute__((aligned(16))) uint8_t lds[81920];

  int wm = wv >> 1, wn = wv & 1;

  const int8_t* Bg = Wq8 + (size_t)o0 * CC;

  // stage B once: chunk j = 2 rows of 512B; swizzle c16 ^= (orow&7)
  {
    int orl = lane >> 5;           // 0..1
    int sl  = lane & 31;           // 16B slot within row
    #pragma unroll
    for (int i=0;i<16;i++){
      int j = wv*16 + i;
      int orow = j*2 + orl;
      int c16 = sl ^ (orow & 7);
      g2lds16(Bg + (size_t)orow*CC + (c16 << 4), lds + j*1024);
    }
  }

  auto STAGE_A = [&](int buf, const int8_t* base, int k0){
    int rl  = lane >> 2;                       // row within 16-row chunk
    int c16 = (lane & 3) ^ ((lane >> 3) & 3);  // pre-swizzled source slot
    #pragma unroll
    for (int i=0;i<2;i++){
      int j = wv*2 + i;
      g2lds16(base + (size_t)(j*16 + rl)*CC + k0 + (c16 << 4),
              lds + 65536 + buf*8192 + j*1024);
    }
  };
  auto READB = [&](int ks, i32x4* dst){
    #pragma unroll
    for (int n=0;n<4;n++){
      int orow = wn*64 + n*16 + (lane & 15);
      int slot = (((ks & 7) << 2) + (lane >> 4)) ^ (lane & 7);
      dst[n] = *(const i32x4*)(lds + orow*512 + (slot << 4));
    }
  };

  i32x4 acc[4][4];
  float st[4][4][4];
  #pragma unroll
  for (int m=0;m<4;m++)
    #pragma unroll
    for (int n=0;n<4;n++){
      acc[m][n] = (i32x4){0,0,0,0};
      #pragma unroll
      for (int j=0;j<4;j++) st[m][n][j] = 0.f;
    }

  float sc[4], bi[4];
  #pragma unroll
  for (int n=0;n<4;n++){
    int og = o0 + wn*64 + n*16 + (lane & 15);
    sc[n] = scales[og];
    bi[n] = bias[og];
  }

  const int8_t* A0 = xs8 + ((size_t)b*VV + v0) * CC;
  STAGE_A(0, A0, 0);
  // no barrier here: first B1 (vmcnt+barrier) covers B and A0

  int anyspike = 0;
  for (int t=0; t<TT; ++t){
    const int8_t* At = xs8 + ((size_t)(t*BB + b)*VV + v0) * CC;
    const int8_t* An = xs8 + ((size_t)((t+1)*BB + b)*VV + v0) * CC;
    #pragma unroll
    for (int ks=0; ks<8; ++ks){
      int g = t*8 + ks;            // global step 0..31 (runtime t is fine)
      int cur = ks & 1;

      // in-loop bcast store: row R = g*1536 + orig, one 4KB NT row per block-
      // step for g<21 (rows 0..32255). Oldest VMEM op of this step.
      bool stored = false;
      if (!STORE && g < 21) {
        size_t R = (size_t)g*1536 + orig;
        f32x4 val = (f32x4){bvv, bvv, bvv, bvv};
        __builtin_nontemporal_store(val, (f32x4*)(outp + R*1024 + tid*4));
        stored = true;
      }

      bool staged = false;
      if (ks < 7)          { STAGE_A(cur^1, At, (ks+1)*64); staged = true; }
      else if (t < TT-1)   { STAGE_A(cur^1, An, 0);         staged = true; }

      // B1: acquire A-buf `cur` (RAW). Storer steps: queue tail is
      // [.., S(g-1), La(g-1), Lb(g-1), S(g), La(g), Lb(g)] -> vmcnt(3)
      // retires everything through Lb(g-1), leaves S(g)+La(g)+Lb(g).
      if (STORE) {
        __syncthreads();
      } else {
        if (staged) {
          if (stored) asm volatile("s_waitcnt vmcnt(3)" ::: "memory");
          else        asm volatile("s_waitcnt vmcnt(2)" ::: "memory");
        } else {
          asm volatile("s_waitcnt vmcnt(0)" ::: "memory");
        }
        __builtin_amdgcn_s_barrier();
      }

      const uint8_t* bufA = lds + 65536 + cur*8192;
      i32x4 af[4], bfr[4];
      #pragma unroll
      for (int m=0;m<4;m++){
        int rr = wm*64 + m*16 + (lane & 15);
        int slot = (lane >> 4) ^ ((lane >> 1) & 3);
        af[m] = *(const i32x4*)(bufA + rr*64 + (slot << 4));
      }
      READB(ks, bfr);

      #pragma unroll
      for (int m=0;m<4;m++)
        #pragma unroll
        for (int n=0;n<4;n++)
          acc[m][n] = __builtin_amdgcn_mfma_i32_16x16x64_i8(af[m], bfr[n], acc[m][n], 0,0,0);

      // B2: release A-buf `cur` (WAR): all my LDS reads done, then barrier
      if (!(t == TT-1 && ks == 7)) {
        if (STORE) {
          __syncthreads();
        } else {
          asm volatile("s_waitcnt lgkmcnt(0)" ::: "memory");
          __builtin_amdgcn_s_barrier();
        }
      }
    }
    // per-t epilogue: dequant + bias + LIF (registers only)
    size_t tb = (size_t)t*BB + b;
    #pragma unroll
    for (int m=0;m<4;m++)
      #pragma unroll
      for (int n=0;n<4;n++)
        #pragma unroll
        for (int j=0;j<4;j++){
          float y = (float)acc[m][n][j] * sc[n] + bi[n];
          float vv = st[m][n][j];
          vv = vv + (y - vv) * 0.5f;
          int s = (vv >= 1.0f) ? 1 : 0;
          anyspike |= s;
          st[m][n][j] = s ? 0.f : vv;
          acc[m][n][j] = 0;
          if (STORE){
            int v  = v0 + wm*64 + m*16 + ((lane >> 4) << 2) + j;
            int og = o0 + wn*64 + n*16 + (lane & 15);
            spk[(tb*VV + v)*(size_t)OO + og] = (uint8_t)s;
          }
        }
  }
  if (!STORE){
    // tail: rows 32256..32767 by blocks orig<512 (same o = orig -> same bvv)
    if (orig < 512){
      size_t R = 32256 + (size_t)orig;
      f32x4 val = (f32x4){bvv, bvv, bvv, bvv};
      __builtin_nontemporal_store(val, (f32x4*)(outp + R*1024 + tid*4));
    }
    unsigned long long any = __ballot(anyspike != 0);
    if (any != 0ull && lane == 0) atomicOr(flags, 1);
  }
}

// ---- gated attention path (runs only if any q/k/v spike) ----
__global__ __launch_bounds__(256) void k_kv(const uint8_t* __restrict__ spk,
                                            float* __restrict__ kv,
                                            const int* __restrict__ flags)
{
  if (flags[0] == 0) return;
  int bid = blockIdx.x;
  int h = bid & 7, b = (bid>>3) & 15, t = bid >> 7;
  size_t tb = (size_t)t*BB + b;
  const uint8_t* kb_g = spk + tb*VV*OO + 512  + h*64;
  const uint8_t* vb_g = spk + tb*VV*OO + 1024 + h*64;
  __shared__ __attribute__((aligned(16))) uint8_t kb[16][64];
  __shared__ __attribute__((aligned(16))) uint8_t vb[16][64];
  int tid = threadIdx.x;
  int d = tid >> 2, e0 = (tid & 3) * 16;
  float acc[16];
  #pragma unroll
  for (int i=0;i<16;i++) acc[i]=0.f;
  for (int n0=0;n0<VV;n0+=16){
    int arr = tid >> 7;
    int rr = (tid >> 3) & 15;
    int ch = (tid & 7) * 8;
    u8x8 val = *(const u8x8*)((arr ? vb_g : kb_g) + (size_t)(n0 + rr)*OO + ch);
    *(u8x8*)&(arr ? vb : kb)[rr][ch] = val;
    __syncthreads();
    #pragma unroll
    for (int nn=0;nn<16;nn++){
      if (kb[nn][d]) {
        #pragma unroll
        for (int i=0;i<16;i++) acc[i] += (vb[nn][e0+i] ? 1.0f : 0.0f);
      }
    }
    __syncthreads();
  }
  float* dst = kv + (((tb*8) + h)*64 + d)*(size_t)64 + e0;
  #pragma unroll
  for (int i=0;i<16;i++) dst[i] = acc[i];
}

__global__ __launch_bounds__(256) void k_o_alif(const uint8_t* __restrict__ spk,
                                                const float* __restrict__ kv,
                                                uint8_t* __restrict__ a,
                                                int* __restrict__ flags)
{
  if (flags[0] == 0) return;
  int bid = blockIdx.x;
  int nt = bid & 7, h = (bid>>3) & 7, b = bid >> 6;
  int n0 = nt * 128;
  __shared__ __attribute__((aligned(16))) float kvb[64][64];
  int tid = threadIdx.x;
  int nl = tid >> 1, e0 = (tid & 1) * 32;
  float st[32];
  #pragma unroll
  for (int i=0;i<32;i++) st[i]=0.f;
  int anyA = 0;
  for (int t=0;t<TT;t++){
    size_t tb = (size_t)t*BB + b;
    const f32x4* src = (const f32x4*)(kv + ((tb*8) + h)*(size_t)4096);
    #pragma unroll
    for (int i=0;i<4;i++) ((f32x4*)kvb)[tid + i*256] = src[tid + i*256];
    __syncthreads();
    const uint8_t* qrow = spk + (tb*VV + n0 + nl)*(size_t)OO + h*64;
    float accv[32];
    #pragma unroll
    for (int i=0;i<32;i++) accv[i]=0.f;
    for (int d8=0; d8<8; d8++){
      u8x8 qv = *(const u8x8*)(qrow + d8*8);
      #pragma unroll
      for (int jj=0;jj<8;jj++){
        if (qv[jj]) {
          int dd = d8*8 + jj;
          #pragma unroll
          for (int i=0;i<32;i++) accv[i] += kvb[dd][e0+i];
        }
      }
    }
    uint8_t* arow = a + (tb*VV + n0 + nl)*(size_t)CC + h*64 + e0;
    #pragma unroll
    for (int i=0;i<32;i++){
      float o = accv[i] * 0.125f;
      float vv = st[i];
      vv = vv + (o - vv)*0.5f;
      bool s = (vv >= 0.5f);
      st[i] = s ? 0.f : vv;
      arow[i] = s ? 1 : 0;
      anyA |= (int)s;
    }
    __syncthreads();
  }
  __shared__ int sA;
  if (tid==0) sA=0;
  __syncthreads();
  if (anyA) sA=1;
  __syncthreads();
  if (tid==0 && sA) atomicOr(flags+1, 1);
}

__global__ __launch_bounds__(256) void k_out_add(const uint8_t* __restrict__ a,
                                                 const unsigned short* __restrict__ WpT,
                                                 float* __restrict__ out,
                                                 const int* __restrict__ flags)
{
  if (flags[1] == 0) return;
  int bid = blockIdx.x;
  int vt = bid & 15, b = (bid>>4) & 15, t = bid >> 8;
  size_t tb = (size_t)t*BB + b;
  int v0 = vt*64;
  int tid = threadIdx.x;
  for (int vi=0; vi<64; vi++){
    int v = v0 + vi;
    const uint8_t* av = a + (tb*VV + v)*(size_t)CC;
    for (int c=0;c<CC;c++){
      if (av[c]) {
        #pragma unroll
        for (int i=0;i<2;i++){
          int o = tid + i*256;
          out[((tb*CC) + o)*(size_t)VV + v] += bf2f(WpT[c*512 + o]);
        }
      }
    }
  }
}

// ---------------- launch ------------------------------------------------------
extern "C" void kernel_launch(void* const* d_in, const int* in_sizes, int n_in,
                              void* d_out, int out_size, void* d_ws, size_t ws_size,
                              hipStream_t stream)
{
  (void)in_sizes; (void)n_in; (void)out_size;
  const float* x  = (const float*)d_in[0];
  const float* Wq = (const float*)d_in[1];
  const float* sq = (const float*)d_in[2];
  const float* bq = (const float*)d_in[3];
  const float* Wk = (const float*)d_in[4];
  const float* sk = (const float*)d_in[5];
  const float* bk = (const float*)d_in[6];
  const float* Wv = (const float*)d_in[7];
  const float* sv = (const float*)d_in[8];
  const float* bv = (const float*)d_in[9];
  const float* Wp = (const float*)d_in[10];
  const float* sp = (const float*)d_in[11];
  const float* bp = (const float*)d_in[12];
  float* out = (float*)d_out;
  uint8_t* ws = (uint8_t*)d_ws;

  if (ws_size < 177483792ull) return;

  int8_t*         xs8   = (int8_t*)(ws + 0);                   // 32 MiB
  int8_t*         Wq8   = (int8_t*)(ws + 33554432ull);         // 768 KiB
  float*          scales= (float*)(ws + 34340864ull);          // 6 KiB
  float*          bias  = (float*)(ws + 34347008ull);          // 6 KiB
  unsigned short* WpT   = (unsigned short*)(ws + 34353152ull); // 512 KiB
  float*          kv    = (float*)(ws + 34877440ull);          // 8 MiB
  uint8_t*        spk   = (uint8_t*)(ws + 43266048ull);        // 96 MiB (fallback)
  uint8_t*        abuf  = (uint8_t*)(ws + 143929344ull);       // 32 MiB (fallback)
  int*            flags = (int*)(ws + 177483776ull);           // 16 B

  k_head_lif_prep<<<2432,256,0,stream>>>(x, xs8, Wq,sq,bq, Wk,sk,bk, Wv,sv,bv,
                                         Wp,sp, Wq8, scales, bias, WpT, flags);
  k_gemm_fused<0><<<1536,256,0,stream>>>(xs8, Wq8, scales, bias, bp, out, spk, flags);
  k_gemm_fused<1><<<1536,256,0,stream>>>(xs8, Wq8, scales, bias, bp, out, spk, flags);
  k_kv<<<512,256,0,stream>>>(spk, kv, flags);
  k_o_alif<<<1024,256,0,stream>>>(spk, kv, abuf, flags);
  k_out_add<<<1024,256,0,stream>>>(abuf, WpT, out, flags);
}